// Round 3
// baseline (17.634 us; speedup 1.0000x reference)
//
#include <hip/hip_runtime.h>

// PathDevelopmentNetwork: FFT convolutions collapse because the filters carry
// exp(-50*t), which is exactly 0 in fp32 for t>=3 (exp(-150) underflows).
// Output is exactly 0 for all lags except the last 3; those are closed-form
// in head prefix sums and total sums of the per-word channel pair.
// Round 3: 1024-thread blocks (16 waves/CU) for memory-level parallelism.

constexpr int T  = 8192;
constexpr int BS = 32;
constexpr int D  = 8;
constexpr int W  = 8;
constexpr int L  = 3;   // exp(-50*l) == 0 in fp32 for l >= 3 (exact, ref is fp32)
constexpr int NT = 1024;
constexpr int NW = NT / 64;

__global__ __launch_bounds__(NT)
void pdn_kernel(const float* __restrict__ x,
                const float* __restrict__ w1,
                const float* __restrict__ b1,
                const float* __restrict__ w2,
                const float* __restrict__ b2,
                float* __restrict__ out)
{
    const int row = blockIdx.x;          // b*W + w
    const int bb  = row >> 3;
    const int wd  = row & 7;
    const int tid = threadIdx.x;
    const float* dx1 = x + ((size_t)bb * D + wd) * T;
    const float* dx2 = x + ((size_t)bb * D + ((wd + 1) & 7)) * T;
    const size_t base = (size_t)row * (T + 1);
    float* orow = out + base;

    // ---- block reduction: s2 = sum(dx2), p = sum(dx1*dx2) ----
    // T/4 = 2048 float4 per array; 1024 threads -> 2 iters, fully unrolled.
    const float4* v1 = (const float4*)dx1;   // rows are 32KB-aligned
    const float4* v2 = (const float4*)dx2;
    float4 a0 = v1[tid], c0 = v2[tid];
    float4 a1 = v1[tid + NT], c1 = v2[tid + NT];

    // ---- vectorized zero of the row, interleaved with the loads above ----
    const int align = (int)((4 - (base & 3)) & 3);   // scalar floats to 16B align
    if (tid < align) orow[tid] = 0.f;
    const int nvec = (T + 1 - align) >> 2;           // ~2048
    const int rem  = (T + 1 - align) - (nvec << 2);
    float4* ov = (float4*)(orow + align);
    const float4 z4 = make_float4(0.f, 0.f, 0.f, 0.f);
    if (tid < nvec) ov[tid] = z4;
    if (tid + NT < nvec) ov[tid + NT] = z4;
    if (tid < rem) orow[align + (nvec << 2) + tid] = 0.f;

    float s2 = (c0.x + c0.y) + (c0.z + c0.w) + (c1.x + c1.y) + (c1.z + c1.w);
    float p  = a0.x * c0.x + a0.y * c0.y + a0.z * c0.z + a0.w * c0.w
             + a1.x * c1.x + a1.y * c1.y + a1.z * c1.z + a1.w * c1.w;

    // ---- wave64 butterfly reduce, then cross-wave via LDS ----
    for (int off = 32; off > 0; off >>= 1) {
        s2 += __shfl_down(s2, off);
        p  += __shfl_down(p,  off);
    }
    __shared__ float sh[2][NW];
    __shared__ float term[4 * L * 5];
    const int wave = tid >> 6, lane = tid & 63;
    if (lane == 0) { sh[0][wave] = s2; sh[1][wave] = p; }

    // ---- parallel FNN taps: term[k][l][h] = tanh(l*w1+b1)*w2, one per lane ----
    if (tid < 4 * L * 5) {
        const int k = tid / (L * 5);
        const int r = tid % (L * 5);
        const int l = r / 5, h = r % 5;
        term[tid] = tanhf((float)l * w1[k * 5 + h] + b1[k * 5 + h]) * w2[k * 5 + h];
    }
    __syncthreads();

    if (tid != 0) return;

    float s2tot = 0.f, ptot = 0.f;
    #pragma unroll
    for (int i = 0; i < NW; ++i) { s2tot += sh[0][i]; ptot += sh[1][i]; }

    // F[k][l] = (b2[k] + sum_h term) * exp(-50 l)
    const float e[L] = {1.0f, expf(-50.0f), expf(-100.0f)};
    float F[4][L];
    for (int k = 0; k < 4; ++k)
        for (int l = 0; l < L; ++l) {
            float acc = b2[k];
            for (int h = 0; h < 5; ++h) acc += term[(k * L + l) * 5 + h];
            F[k][l] = acc * e[l];
        }

    // heads: S1(j) = sum_{u<j} dx1[u], Q(j) = sum_{t<j} dx2[t]*S1(t)
    float S1[L], Q[L];
    S1[0] = 0.f; Q[0] = 0.f;
    for (int j = 1; j < L; ++j) {
        S1[j] = S1[j - 1] + dx1[j - 1];
        Q[j]  = Q[j - 1] + dx2[j - 1] * S1[j - 1];
    }
    // tails: S2v[i] = sum_{t<T-i} dx2[t];  Pv[i] = sum_{t<T-i} dx1[t]*dx2[t]
    float S2v[2 * L - 1], Pv[2 * L - 1];
    S2v[0] = s2tot; Pv[0] = ptot;
    for (int i = 1; i < 2 * L - 1; ++i) {
        S2v[i] = S2v[i - 1] - dx2[T - i];
        Pv[i]  = Pv[i - 1]  - dx1[T - i] * dx2[T - i];
    }
    float Gsum = 0.f, GPsum = 0.f;
    for (int l = 0; l < L; ++l) { Gsum += F[2][l]; GPsum += F[3][l]; }

    // out[T-m] = 0.5*(AA*Gsum + BA*GPsum + CA*CB + DA*DB + EA*EB + FA*FB)
    for (int m = 0; m < L; ++m) {
        float AA = 0, BA = 0, CA = 0, DA = 0, EA = 0, FA = 0;
        for (int l = m; l < L; ++l) {
            const float q = Q[l - m], s1 = S1[l - m];
            AA += F[0][l] * q;   BA += F[1][l] * q;
            CA += F[0][l] * s1;  DA += F[1][l] * s1;
            EA += F[0][l];       FA += F[1][l];
        }
        float CB = 0, DB = 0, EB = 0, FB = 0;
        for (int l = 0; l < L; ++l) {
            CB += F[2][l] * S2v[m + l]; DB += F[3][l] * S2v[m + l];
            EB += F[2][l] * Pv[m + l];  FB += F[3][l] * Pv[m + l];
        }
        orow[T - m] = 0.5f * (AA * Gsum + BA * GPsum + CA * CB + DA * DB + EA * EB + FA * FB);
    }
}

extern "C" void kernel_launch(void* const* d_in, const int* in_sizes, int n_in,
                              void* d_out, int out_size, void* d_ws, size_t ws_size,
                              hipStream_t stream)
{
    const float* x  = (const float*)d_in[0];
    const float* w1 = (const float*)d_in[1];
    const float* b1 = (const float*)d_in[2];
    const float* w2 = (const float*)d_in[3];
    const float* b2 = (const float*)d_in[4];
    float* out = (float*)d_out;

    pdn_kernel<<<BS * W, NT, 0, stream>>>(x, w1, b1, w2, b2, out);
}

// Round 4
// 12.757 us; speedup vs baseline: 1.3823x; 1.3823x over previous
//
#include <hip/hip_runtime.h>

// PathDevelopmentNetwork: FFT convolutions collapse because the filters carry
// exp(-50*t), which is exactly 0 in fp32 for t>=3 (exp(-150) underflows).
// Output is exactly 0 for all lags except the last 3; those are closed-form
// in head prefix sums and total sums of the per-word channel pair.
// Round 4: two-kernel split. A = wide-grid fill+partial-reduce (TLP like the
// 6.7TB/s fill kernel); B = per-row combine + epilogue. No atomics, no
// cross-block ordering assumptions -> deterministic.

constexpr int T  = 8192;
constexpr int BS = 32;
constexpr int D  = 8;
constexpr int W  = 8;
constexpr int L  = 3;    // exp(-50*l) == 0 in fp32 for l >= 3 (exact, ref is fp32)
constexpr int SL = 8;    // slices per row
constexpr int CH = T / SL;   // 1024 elements per slice

// ---------------- Kernel A: zero-fill + per-slice partial reduction ----------
__global__ __launch_bounds__(256)
void pdn_reduce_fill(const float* __restrict__ x,
                     float* __restrict__ out,
                     float2* __restrict__ partials)
{
    const int bid = blockIdx.x;          // row*SL + slice
    const int row = bid >> 3;
    const int sl  = bid & 7;
    const int bb  = row >> 3;
    const int wd  = row & 7;
    const int tid = threadIdx.x;

    const float* dx1 = x + ((size_t)bb * D + wd) * T + sl * CH;
    const float* dx2 = x + ((size_t)bb * D + ((wd + 1) & 7)) * T + sl * CH;

    // one float4 per input per thread (256*4 = 1024 elements)
    const float4 a = ((const float4*)dx1)[tid];
    const float4 c = ((const float4*)dx2)[tid];

    // ---- zero-fill this slice of the output row ----
    const size_t base = (size_t)row * (T + 1) + (size_t)sl * CH;
    float* o = out + base;
    const int align = (int)((4 - (base & 3)) & 3);
    if (tid < align) o[tid] = 0.f;
    const int nv  = (CH - align) >> 2;
    const int rem = CH - align - (nv << 2);
    float4* ov = (float4*)(o + align);
    const float4 z4 = make_float4(0.f, 0.f, 0.f, 0.f);
    if (tid < nv) ov[tid] = z4;
    if (tid < rem) o[align + (nv << 2) + tid] = 0.f;
    if (sl == SL - 1 && tid == 0) out[(size_t)row * (T + 1) + T] = 0.f;

    // ---- reduce: s2 = sum(dx2 slice), p = sum(dx1*dx2 slice) ----
    float s2 = (c.x + c.y) + (c.z + c.w);
    float p  = a.x * c.x + a.y * c.y + a.z * c.z + a.w * c.w;
    for (int off = 32; off > 0; off >>= 1) {
        s2 += __shfl_down(s2, off);
        p  += __shfl_down(p,  off);
    }
    __shared__ float sh[2][4];
    const int wave = tid >> 6, lane = tid & 63;
    if (lane == 0) { sh[0][wave] = s2; sh[1][wave] = p; }
    __syncthreads();
    if (tid == 0) {
        float s = sh[0][0] + sh[0][1] + sh[0][2] + sh[0][3];
        float q = sh[1][0] + sh[1][1] + sh[1][2] + sh[1][3];
        partials[bid] = make_float2(s, q);
    }
}

// ---------------- Kernel B: combine partials + closed-form epilogue ----------
__global__ __launch_bounds__(64)
void pdn_epilogue(const float* __restrict__ x,
                  const float* __restrict__ w1,
                  const float* __restrict__ b1,
                  const float* __restrict__ w2,
                  const float* __restrict__ b2,
                  const float2* __restrict__ partials,
                  float* __restrict__ out)
{
    const int row  = blockIdx.x;
    const int lane = threadIdx.x;
    const int bb   = row >> 3;
    const int wd   = row & 7;
    const float* dx1 = x + ((size_t)bb * D + wd) * T;
    const float* dx2 = x + ((size_t)bb * D + ((wd + 1) & 7)) * T;
    float* orow = out + (size_t)row * (T + 1);

    // parallel FNN taps: term[k][l][h] = tanh(l*w1+b1)*w2  (60 lanes)
    __shared__ float term[4 * L * 5];
    if (lane < 4 * L * 5) {
        const int k = lane / (L * 5);
        const int r = lane % (L * 5);
        const int l = r / 5, h = r % 5;
        term[lane] = tanhf((float)l * w1[k * 5 + h] + b1[k * 5 + h]) * w2[k * 5 + h];
    }

    // combine the 8 slice partials (fixed shuffle tree -> deterministic)
    float s2 = 0.f, p = 0.f;
    if (lane < SL) {
        const float2 t = partials[row * SL + lane];
        s2 = t.x; p = t.y;
    }
    for (int off = SL / 2; off > 0; off >>= 1) {
        s2 += __shfl_down(s2, off);
        p  += __shfl_down(p,  off);
    }
    __syncthreads();
    if (lane != 0) return;

    const float s2tot = s2, ptot = p;

    // F[k][l] = (b2[k] + sum_h term) * exp(-50 l)
    const float e[L] = {1.0f, expf(-50.0f), expf(-100.0f)};
    float F[4][L];
    for (int k = 0; k < 4; ++k)
        for (int l = 0; l < L; ++l) {
            float acc = b2[k];
            for (int h = 0; h < 5; ++h) acc += term[(k * L + l) * 5 + h];
            F[k][l] = acc * e[l];
        }

    // heads: S1(j) = sum_{u<j} dx1[u], Q(j) = sum_{t<j} dx2[t]*S1(t)
    float S1[L], Q[L];
    S1[0] = 0.f; Q[0] = 0.f;
    for (int j = 1; j < L; ++j) {
        S1[j] = S1[j - 1] + dx1[j - 1];
        Q[j]  = Q[j - 1] + dx2[j - 1] * S1[j - 1];
    }
    // tails: S2v[i] = sum_{t<T-i} dx2[t];  Pv[i] = sum_{t<T-i} dx1[t]*dx2[t]
    float S2v[2 * L - 1], Pv[2 * L - 1];
    S2v[0] = s2tot; Pv[0] = ptot;
    for (int i = 1; i < 2 * L - 1; ++i) {
        S2v[i] = S2v[i - 1] - dx2[T - i];
        Pv[i]  = Pv[i - 1]  - dx1[T - i] * dx2[T - i];
    }
    float Gsum = 0.f, GPsum = 0.f;
    for (int l = 0; l < L; ++l) { Gsum += F[2][l]; GPsum += F[3][l]; }

    // out[T-m] = 0.5*(AA*Gsum + BA*GPsum + CA*CB + DA*DB + EA*EB + FA*FB)
    for (int m = 0; m < L; ++m) {
        float AA = 0, BA = 0, CA = 0, DA = 0, EA = 0, FA = 0;
        for (int l = m; l < L; ++l) {
            const float q = Q[l - m], s1 = S1[l - m];
            AA += F[0][l] * q;   BA += F[1][l] * q;
            CA += F[0][l] * s1;  DA += F[1][l] * s1;
            EA += F[0][l];       FA += F[1][l];
        }
        float CB = 0, DB = 0, EB = 0, FB = 0;
        for (int l = 0; l < L; ++l) {
            CB += F[2][l] * S2v[m + l]; DB += F[3][l] * S2v[m + l];
            EB += F[2][l] * Pv[m + l];  FB += F[3][l] * Pv[m + l];
        }
        orow[T - m] = 0.5f * (AA * Gsum + BA * GPsum + CA * CB + DA * DB + EA * EB + FA * FB);
    }
}

extern "C" void kernel_launch(void* const* d_in, const int* in_sizes, int n_in,
                              void* d_out, int out_size, void* d_ws, size_t ws_size,
                              hipStream_t stream)
{
    const float* x  = (const float*)d_in[0];
    const float* w1 = (const float*)d_in[1];
    const float* b1 = (const float*)d_in[2];
    const float* w2 = (const float*)d_in[3];
    const float* b2 = (const float*)d_in[4];
    float* out = (float*)d_out;
    float2* partials = (float2*)d_ws;    // 2048 float2 = 16 KB

    pdn_reduce_fill<<<BS * W * SL, 256, 0, stream>>>(x, out, partials);
    pdn_epilogue<<<BS * W, 64, 0, stream>>>(x, w1, b1, w2, b2, partials, out);
}

// Round 5
// 9.959 us; speedup vs baseline: 1.7706x; 1.2809x over previous
//
#include <hip/hip_runtime.h>

// PathDevelopmentNetwork: FFT convolutions collapse because the filters carry
// exp(-50*t), which is exactly 0 in fp32 for t>=3 (exp(-150) underflows).
// Output is exactly 0 for all lags except the last 3; those are closed-form
// in head prefix sums and total sums of the per-word channel pair.
// Round 5: ONE dispatch (per-dispatch overhead ~4.5us dominated R4's split).
// Block-role split: 2048 fill blocks (zero stores, skip row tails) +
// 256 row blocks (full-row reduce + epilogue writes the 3 tail values).
// Disjoint writer sets -> no race, no ordering assumption, deterministic.

constexpr int T  = 8192;
constexpr int BS = 32;
constexpr int D  = 8;
constexpr int W  = 8;
constexpr int L  = 3;            // exp(-50*l)==0 in fp32 for l>=3 (exact)
constexpr int NFILL = BS * W * 8;   // 2048 fill blocks, 1024 elems each
constexpr int CH = 1024;

__global__ __launch_bounds__(256)
void pdn_fused(const float* __restrict__ x,
               const float* __restrict__ w1,
               const float* __restrict__ b1,
               const float* __restrict__ w2,
               const float* __restrict__ b2,
               float* __restrict__ out)
{
    const int bid = blockIdx.x;
    const int tid = threadIdx.x;

    if (bid < NFILL) {
        // ---------- fill role: zero one slice, skip row-local [T-2, T] ----------
        const int row = bid >> 3;
        const int sl  = bid & 7;
        const size_t base = (size_t)row * (T + 1) + (size_t)sl * CH;
        float* o = out + base;
        const int n = (sl == 7) ? CH - 2 : CH;      // slice 7 stops at T-2
        const int align = (int)((4 - (base & 3)) & 3);
        if (tid < align) o[tid] = 0.f;
        const int nv  = (n - align) >> 2;
        const int rem = n - align - (nv << 2);
        float4* ov = (float4*)(o + align);
        if (tid < nv) ov[tid] = make_float4(0.f, 0.f, 0.f, 0.f);
        if (tid < rem) o[align + (nv << 2) + tid] = 0.f;
        return;
    }

    // ---------- row role: full-row reduction + closed-form epilogue ----------
    const int row = bid - NFILL;
    const int bb  = row >> 3;
    const int wd  = row & 7;
    const float* dx1 = x + ((size_t)bb * D + wd) * T;
    const float* dx2 = x + ((size_t)bb * D + ((wd + 1) & 7)) * T;
    float* orow = out + (size_t)row * (T + 1);

    const float4* v1 = (const float4*)dx1;   // rows are 32KB-aligned
    const float4* v2 = (const float4*)dx2;
    float s2 = 0.f, p = 0.f;
    #pragma unroll
    for (int i = 0; i < 8; ++i) {
        const float4 a = v1[tid + 256 * i];
        const float4 c = v2[tid + 256 * i];
        s2 += (c.x + c.y) + (c.z + c.w);
        p  += a.x * c.x + a.y * c.y + a.z * c.z + a.w * c.w;
    }
    for (int off = 32; off > 0; off >>= 1) {
        s2 += __shfl_down(s2, off);
        p  += __shfl_down(p,  off);
    }
    __shared__ float sh[2][4];
    __shared__ float term[4 * L * 5];
    const int wave = tid >> 6, lane = tid & 63;
    if (lane == 0) { sh[0][wave] = s2; sh[1][wave] = p; }

    // parallel FNN taps: term[k][l][h] = tanh(l*w1+b1)*w2 (60 lanes)
    if (tid < 4 * L * 5) {
        const int k = tid / (L * 5);
        const int r = tid % (L * 5);
        const int l = r / 5, h = r % 5;
        term[tid] = tanhf((float)l * w1[k * 5 + h] + b1[k * 5 + h]) * w2[k * 5 + h];
    }
    __syncthreads();
    if (tid != 0) return;

    const float s2tot = sh[0][0] + sh[0][1] + sh[0][2] + sh[0][3];
    const float ptot  = sh[1][0] + sh[1][1] + sh[1][2] + sh[1][3];

    // F[k][l] = (b2[k] + sum_h term) * exp(-50 l)
    const float e[L] = {1.0f, expf(-50.0f), expf(-100.0f)};
    float F[4][L];
    for (int k = 0; k < 4; ++k)
        for (int l = 0; l < L; ++l) {
            float acc = b2[k];
            for (int h = 0; h < 5; ++h) acc += term[(k * L + l) * 5 + h];
            F[k][l] = acc * e[l];
        }

    // heads: S1(j) = sum_{u<j} dx1[u], Q(j) = sum_{t<j} dx2[t]*S1(t)
    float S1[L], Q[L];
    S1[0] = 0.f; Q[0] = 0.f;
    for (int j = 1; j < L; ++j) {
        S1[j] = S1[j - 1] + dx1[j - 1];
        Q[j]  = Q[j - 1] + dx2[j - 1] * S1[j - 1];
    }
    // tails: S2v[i] = sum_{t<T-i} dx2[t];  Pv[i] = sum_{t<T-i} dx1[t]*dx2[t]
    float S2v[2 * L - 1], Pv[2 * L - 1];
    S2v[0] = s2tot; Pv[0] = ptot;
    for (int i = 1; i < 2 * L - 1; ++i) {
        S2v[i] = S2v[i - 1] - dx2[T - i];
        Pv[i]  = Pv[i - 1]  - dx1[T - i] * dx2[T - i];
    }
    float Gsum = 0.f, GPsum = 0.f;
    for (int l = 0; l < L; ++l) { Gsum += F[2][l]; GPsum += F[3][l]; }

    // out[T-m] = 0.5*(AA*Gsum + BA*GPsum + CA*CB + DA*DB + EA*EB + FA*FB)
    for (int m = 0; m < L; ++m) {
        float AA = 0, BA = 0, CA = 0, DA = 0, EA = 0, FA = 0;
        for (int l = m; l < L; ++l) {
            const float q = Q[l - m], s1 = S1[l - m];
            AA += F[0][l] * q;   BA += F[1][l] * q;
            CA += F[0][l] * s1;  DA += F[1][l] * s1;
            EA += F[0][l];       FA += F[1][l];
        }
        float CB = 0, DB = 0, EB = 0, FB = 0;
        for (int l = 0; l < L; ++l) {
            CB += F[2][l] * S2v[m + l]; DB += F[3][l] * S2v[m + l];
            EB += F[2][l] * Pv[m + l];  FB += F[3][l] * Pv[m + l];
        }
        orow[T - m] = 0.5f * (AA * Gsum + BA * GPsum + CA * CB + DA * DB + EA * EB + FA * FB);
    }
}

extern "C" void kernel_launch(void* const* d_in, const int* in_sizes, int n_in,
                              void* d_out, int out_size, void* d_ws, size_t ws_size,
                              hipStream_t stream)
{
    const float* x  = (const float*)d_in[0];
    const float* w1 = (const float*)d_in[1];
    const float* b1 = (const float*)d_in[2];
    const float* w2 = (const float*)d_in[3];
    const float* b2 = (const float*)d_in[4];
    float* out = (float*)d_out;

    pdn_fused<<<NFILL + BS * W, 256, 0, stream>>>(x, w1, b1, w2, b2, out);
}